// Round 2
// baseline (222.258 us; speedup 1.0000x reference)
//
#include <hip/hip_runtime.h>
#include <math.h>

// DSHW (double-seasonal Holt-Winters, multiplicative) on MI355X.
// The recursion is unstable (reference fcast reaches ~8e10 from y~10), so
// perturbations injected mid-scan get amplified ~e^16+. All state math runs
// in f64 so our trajectory tracks the numpy f64 reference to ~1e-9 relative;
// outputs are cast to f32 at store time.
// One thread per (batch, feature) series; 1024 series; 32 lanes/block so the
// 192-phase double-precision seasonal state (48 KiB) fits static LDS.

#define P1c   24
#define P2c   168
#define NSTEP 512
#define BSc   64
#define NFc   16
#define MAXH  336
#define NT    32   // lanes per block; 48 KiB LDS for f64 state

// output offsets (floats), concatenated in reference return order
#define OFF_FC   0
#define OFF_YH   (BSc * MAXH * NFc)                       // 344064
#define OFF_E    (OFF_YH + BSc * NSTEP * NFc)             // 868352
#define OFF_IC   (OFF_E  + BSc * NSTEP * NFc)             // 1392640
#define OFF_WC   (OFF_IC + BSc * P1c * NFc)               // 1417216
#define OFF_T    (OFF_WC + BSc * P2c * NFc)               // 1589248
#define OFF_S    (OFF_T  + BSc * NFc)                     // 1590272

__global__ __launch_bounds__(NT, 1)
void dshw_kernel(const float* __restrict__ y,
                 const float* __restrict__ alphas,
                 const float* __restrict__ betas,
                 const float* __restrict__ gammas,
                 const float* __restrict__ omegas,
                 float* __restrict__ out)
{
    __shared__ double sIc[P1c][NT];   // 6 KiB
    __shared__ double sWc[P2c][NT];   // 42 KiB

    const int tid = threadIdx.x;
    const int g   = blockIdx.x * NT + tid;
    const int bb  = g >> 4;          // batch index
    const int f   = g & 15;          // feature index

    const float* __restrict__ yb = y + (size_t)bb * NSTEP * NFc + f;

    // sigmoid(params) in f64 — once per thread
    const double al = 1.0 / (1.0 + exp(-(double)alphas[f]));
    const double be = 1.0 / (1.0 + exp(-(double)betas[f]));
    const double ga = 1.0 / (1.0 + exp(-(double)gammas[f]));
    const double om = 1.0 / (1.0 + exp(-(double)omegas[f]));

    // ---------------- init params (mult_init_params), all f64 ----------------
    double sum48 = 0.0;
    #pragma unroll
    for (int ph = 0; ph < P1c; ++ph) {
        double v0 = (double)yb[ph * NFc];
        double v1 = (double)yb[(ph + P1c) * NFc];
        sIc[ph][tid] = 0.5 * (v0 + v1);
        sum48 += v0 + v1;
    }
    const double inv_mean48 = 48.0 / sum48;
    #pragma unroll
    for (int ph = 0; ph < P1c; ++ph) sIc[ph][tid] *= inv_mean48;

    double sum168a = 0.0, sum168b = 0.0;
    for (int i = 0; i < P2c; ++i) {
        double v0 = (double)yb[i * NFc];
        double v1 = (double)yb[(i + P2c) * NFc];
        sWc[i][tid] = 0.5 * (v0 + v1);
        sum168a += v0;
        sum168b += v1;
    }
    const double mean336 = (sum168a + sum168b) * (1.0 / 336.0);
    for (int i = 0; i < P2c; ++i) {
        sWc[i][tid] = (sWc[i][tid] / mean336) / sIc[i % P1c][tid];
    }

    double tt = 0.5 * ((sum168a - sum168b) * (1.0 / (168.0 * 168.0)) +
                       ((double)yb[(P2c - 1) * NFc] - (double)yb[0]) * (1.0 / 168.0));
    double ss = mean336 - 168.5 * tt;

    // ---------------- the 512-step scan ----------------
    float* __restrict__ yh_o = out + OFF_YH + (size_t)bb * NSTEP * NFc + f;
    float* __restrict__ e_o  = out + OFF_E  + (size_t)bb * NSTEP * NFc + f;

    int i1 = 0, i2 = 0;      // phase consumed/written at this step
    int i1p = 2, i2p = 2;    // prefetch phase (step+2)

    double Icv0 = sIc[0][tid], Icv1 = sIc[1][tid];
    double wcv0 = sWc[0][tid], wcv1 = sWc[1][tid];
    double yt0 = (double)yb[0 * NFc], yt1 = (double)yb[1 * NFc];
    double yt2 = (double)yb[2 * NFc], yt3 = (double)yb[3 * NFc];

    #pragma unroll 4
    for (int step = 0; step < NSTEP; ++step) {
        // prefetch step+2 state (phases distinct from the two pending writes)
        double Icv2 = sIc[i1p][tid];
        double wcv2 = sWc[i2p][tid];
        int    pidx = step + 4; pidx = (pidx < NSTEP) ? pidx : (NSTEP - 1);
        double yt4  = (double)yb[pidx * NFc];

        double iw     = Icv0 * wcv0;
        double spt    = ss + tt;
        double yhat   = spt * iw;
        double inv_iw = 1.0 / iw;                  // IEEE f64 divide
        double u      = yt0 * inv_iw;
        double snew   = al * u + (1.0 - al) * spt;
        double tnew   = be * (snew - ss) + (1.0 - be) * tt;
        double q      = yt0 / snew;                // IEEE f64 divide
        double icn    = ga * (q * (inv_iw * Icv0)) + (1.0 - ga) * Icv0; // /wcv0
        double wcn    = om * (q * (inv_iw * wcv0)) + (1.0 - om) * wcv0; // /Icv0

        sIc[i1][tid] = icn;
        sWc[i2][tid] = wcn;
        yh_o[step * NFc] = (float)yhat;
        e_o[step * NFc]  = (float)(yt0 - yhat);

        ss = snew; tt = tnew;
        Icv0 = Icv1; Icv1 = Icv2;
        wcv0 = wcv1; wcv1 = wcv2;
        yt0 = yt1; yt1 = yt2; yt2 = yt3; yt3 = yt4;
        i1  = (i1  + 1 == P1c) ? 0 : i1  + 1;
        i2  = (i2  + 1 == P2c) ? 0 : i2  + 1;
        i1p = (i1p + 1 == P1c) ? 0 : i1p + 1;
        i2p = (i2p + 1 == P2c) ? 0 : i2p + 1;
    }

    // ---------------- epilogue ----------------
    // next phase after 512 steps: 512%24 = 512%168 = 8
    // rolled Ic[j] = raw[(j+8)%24]; rolled wc[j] = raw[(j+8)%168]

    float* __restrict__ fc_o = out + OFF_FC + (size_t)bb * MAXH * NFc + f;
    {
        int k1 = 8, k2 = 8;
        for (int k = 0; k < MAXH; ++k) {
            double cb = sIc[k1][tid];
            double cc = sWc[k2][tid];
            double ca = ss + (double)(k + 1) * tt;
            fc_o[k * NFc] = (float)(ca * cb * cc);
            k1 = (k1 + 1 == P1c) ? 0 : k1 + 1;
            k2 = (k2 + 1 == P2c) ? 0 : k2 + 1;
        }
    }

    {
        float* __restrict__ ic_o = out + OFF_IC + (size_t)bb * P1c * NFc + f;
        int k1 = 8;
        #pragma unroll
        for (int j = 0; j < P1c; ++j) {
            ic_o[j * NFc] = (float)sIc[k1][tid];
            k1 = (k1 + 1 == P1c) ? 0 : k1 + 1;
        }
    }
    {
        float* __restrict__ wc_o = out + OFF_WC + (size_t)bb * P2c * NFc + f;
        int k2 = 8;
        for (int j = 0; j < P2c; ++j) {
            wc_o[j * NFc] = (float)sWc[k2][tid];
            k2 = (k2 + 1 == P2c) ? 0 : k2 + 1;
        }
    }

    out[OFF_T + bb * NFc + f] = (float)tt;
    out[OFF_S + bb * NFc + f] = (float)ss;
}

extern "C" void kernel_launch(void* const* d_in, const int* in_sizes, int n_in,
                              void* d_out, int out_size, void* d_ws, size_t ws_size,
                              hipStream_t stream)
{
    const float* y      = (const float*)d_in[0];
    const float* alphas = (const float*)d_in[1];
    const float* betas  = (const float*)d_in[2];
    const float* gammas = (const float*)d_in[3];
    const float* omegas = (const float*)d_in[4];
    // d_in[5] = phis — unused (enable_ar=False)
    float* out = (float*)d_out;

    dim3 grid((BSc * NFc) / NT);   // 32 blocks
    dim3 block(NT);                // 32 lanes (half-wave active)
    hipLaunchKernelGGL(dshw_kernel, grid, block, 0, stream,
                       y, alphas, betas, gammas, omegas, out);
}

// Round 3
// 206.350 us; speedup vs baseline: 1.0771x; 1.0771x over previous
//
#include <hip/hip_runtime.h>
#include <math.h>

// DSHW (double-seasonal Holt-Winters) on MI355X — R3: software-pipelined scan.
// Numerics: the recursion is unstable (fcast ~8e10 from y~10); all state math
// runs in f64 and every f64 expression is kept textually identical to the R2
// passing kernel so the output bits (absmax 1.61e9 < 1.675e9 thr) are preserved.
// Scheduling changes only:
//  - B-stage (iw, inv_iw=1/iw, u, inv*Ic, inv*wc) hoisted 2 steps EARLY
//    (operands are prefetched state -> bit-identical, divide off the chain)
//  - D-stage (q=yt/snew, icn, wcn, LDS writes) deferred 2 steps LATE
//    (consumers are 22+ steps away -> bit-identical, divide off the chain)
//  - epilogue moved to a parallel kernel reading raw f64 state from d_ws
//    (same f64 expressions -> same bits)

#define P1c   24
#define P2c   168
#define NSTEP 512
#define BSc   64
#define NFc   16
#define MAXH  336
#define NT    32

#define OFF_FC   0
#define OFF_YH   (BSc * MAXH * NFc)                       // 344064
#define OFF_E    (OFF_YH + BSc * NSTEP * NFc)             // 868352
#define OFF_IC   (OFF_E  + BSc * NSTEP * NFc)             // 1392640
#define OFF_WC   (OFF_IC + BSc * P1c * NFc)               // 1417216
#define OFF_T    (OFF_WC + BSc * P2c * NFc)               // 1589248
#define OFF_S    (OFF_T  + BSc * NFc)                     // 1590272

#define NSERIES  (BSc * NFc)          // 1024
#define WS_ITEMS (P1c + P2c + 2)      // 194 doubles per series, item-major
#define WS_NEED  ((size_t)WS_ITEMS * NSERIES * sizeof(double))

// ---------------------------------------------------------------------------
// Kernel 1: init + 512-step scan, dump raw f64 state to ws.
// ---------------------------------------------------------------------------
__global__ __launch_bounds__(NT, 1)
void dshw_scan(const float* __restrict__ y,
               const float* __restrict__ alphas,
               const float* __restrict__ betas,
               const float* __restrict__ gammas,
               const float* __restrict__ omegas,
               float* __restrict__ out,
               double* __restrict__ ws)
{
    __shared__ double sIc[P1c][NT];
    __shared__ double sWc[P2c][NT];

    const int tid = threadIdx.x;
    const int g   = blockIdx.x * NT + tid;
    const int bb  = g >> 4;
    const int f   = g & 15;

    const float* __restrict__ yb = y + (size_t)bb * NSTEP * NFc + f;

    const double al = 1.0 / (1.0 + exp(-(double)alphas[f]));
    const double be = 1.0 / (1.0 + exp(-(double)betas[f]));
    const double ga = 1.0 / (1.0 + exp(-(double)gammas[f]));
    const double om = 1.0 / (1.0 + exp(-(double)omegas[f]));

    // ---------------- init (identical expressions to R2) ----------------
    double sum48 = 0.0;
    #pragma unroll
    for (int ph = 0; ph < P1c; ++ph) {
        double v0 = (double)yb[ph * NFc];
        double v1 = (double)yb[(ph + P1c) * NFc];
        sIc[ph][tid] = 0.5 * (v0 + v1);
        sum48 += v0 + v1;
    }
    const double inv_mean48 = 48.0 / sum48;
    #pragma unroll
    for (int ph = 0; ph < P1c; ++ph) sIc[ph][tid] *= inv_mean48;

    double sum168a = 0.0, sum168b = 0.0;
    #pragma unroll 8
    for (int i = 0; i < P2c; ++i) {
        double v0 = (double)yb[i * NFc];
        double v1 = (double)yb[(i + P2c) * NFc];
        sWc[i][tid] = 0.5 * (v0 + v1);
        sum168a += v0;
        sum168b += v1;
    }
    const double mean336 = (sum168a + sum168b) * (1.0 / 336.0);
    #pragma unroll 8
    for (int i = 0; i < P2c; ++i) {
        sWc[i][tid] = (sWc[i][tid] / mean336) / sIc[i % P1c][tid];
    }

    double tt = 0.5 * ((sum168a - sum168b) * (1.0 / (168.0 * 168.0)) +
                       ((double)yb[(P2c - 1) * NFc] - (double)yb[0]) * (1.0 / 168.0));
    double ss = mean336 - 168.5 * tt;

    // ---------------- pipelined scan ----------------
    float* __restrict__ yh_o = out + OFF_YH + (size_t)bb * NSTEP * NFc + f;
    float* __restrict__ e_o  = out + OFF_E  + (size_t)bb * NSTEP * NFc + f;

    // y queue: ytq0..ytq5 = y_{s-2}..y_{s+3} at iter s (main loop starts s=2)
    double ytq0 = (double)yb[0 * NFc];
    double ytq1 = (double)yb[1 * NFc];
    double ytq2 = (double)yb[2 * NFc];
    double ytq3 = (double)yb[3 * NFc];
    double ytq4 = (double)yb[4 * NFc];
    double ytq5 = (double)yb[5 * NFc];

    // seasonal state for steps 0..3 (init values, no writes yet)
    double Icq0 = sIc[0][tid], Icq1 = sIc[1][tid], Icq2 = sIc[2][tid], Icq3 = sIc[3][tid];
    double wcq0 = sWc[0][tid], wcq1 = sWc[1][tid], wcq2 = sWc[2][tid], wcq3 = sWc[3][tid];

    // B-stage for steps 0..3 (same expressions: iw=Ic*wc, inv=1/iw, u=yt*inv,
    // pI=inv*Ic, pW=inv*wc — identical operand values to R2's per-step math)
    double iw_0 = Icq0 * wcq0;  double inv_0 = 1.0 / iw_0;
    double iw_1 = Icq1 * wcq1;  double inv_1 = 1.0 / iw_1;
    double iw_2 = Icq2 * wcq2;  double inv_2 = 1.0 / iw_2;
    double iw_3 = Icq3 * wcq3;  double inv_3 = 1.0 / iw_3;
    double u_0 = ytq0 * inv_0;  double pIq0 = inv_0 * Icq0;  double pWq0 = inv_0 * wcq0;
    double u_1 = ytq1 * inv_1;  double pIq1 = inv_1 * Icq1;  double pWq1 = inv_1 * wcq1;
    double uq0 = ytq2 * inv_2;  double pIq2 = inv_2 * Icq2;  double pWq2 = inv_2 * wcq2;
    double uq1 = ytq3 * inv_3;  double pIq3 = inv_3 * Icq3;  double pWq3 = inv_3 * wcq3;
    double iwq0 = iw_2, iwq1 = iw_3;

    double snewq0, snewq1;

    // peeled C for step 0
    {
        double spt  = ss + tt;
        double yhat = spt * iw_0;
        double snew = al * u_0 + (1.0 - al) * spt;
        double tnew = be * (snew - ss) + (1.0 - be) * tt;
        yh_o[0] = (float)yhat;
        e_o[0]  = (float)(ytq0 - yhat);
        snewq0 = snew;
        ss = snew; tt = tnew;
    }
    // peeled C for step 1
    {
        double spt  = ss + tt;
        double yhat = spt * iw_1;
        double snew = al * u_1 + (1.0 - al) * spt;
        double tnew = be * (snew - ss) + (1.0 - be) * tt;
        yh_o[1 * NFc] = (float)yhat;
        e_o[1 * NFc]  = (float)(ytq1 - yhat);
        snewq1 = snew;
        ss = snew; tt = tnew;
    }

    int i1p = 4, i2p = 4;   // prefetch phase for step s+2 at s=2
    int i1w = 0, i2w = 0;   // write phase for step s-2 at s=2

    #pragma unroll 6
    for (int s = 2; s < NSTEP; ++s) {
        // A: prefetch state for step s+2, y for step s+4
        double IcP = sIc[i1p][tid];
        double wcP = sWc[i2p][tid];
        int pidx = s + 4; pidx = (pidx < NSTEP) ? pidx : (NSTEP - 1);
        double ytP = (double)yb[pidx * NFc];

        // B: off-chain work for step s+2 (divide #1)
        double iw2  = IcP * wcP;
        double inv2 = 1.0 / iw2;
        double u2   = ytq4 * inv2;
        double pI4  = inv2 * IcP;
        double pW4  = inv2 * wcP;

        // C: the dependency chain for step s
        double spt  = ss + tt;
        double yhat = spt * iwq0;
        double snew = al * uq0 + (1.0 - al) * spt;
        double tnew = be * (snew - ss) + (1.0 - be) * tt;
        yh_o[s * NFc] = (float)yhat;
        e_o[s * NFc]  = (float)(ytq2 - yhat);

        // D: deferred work for step s-2 (divide #2)
        double q   = ytq0 / snewq0;
        double icn = ga * (q * pIq0) + (1.0 - ga) * Icq0;
        double wcn = om * (q * pWq0) + (1.0 - om) * wcq0;
        sIc[i1w][tid] = icn;
        sWc[i2w][tid] = wcn;

        // shifts
        ss = snew; tt = tnew;
        iwq0 = iwq1; iwq1 = iw2;
        uq0  = uq1;  uq1  = u2;
        pIq0 = pIq1; pIq1 = pIq2; pIq2 = pIq3; pIq3 = pI4;
        pWq0 = pWq1; pWq1 = pWq2; pWq2 = pWq3; pWq3 = pW4;
        Icq0 = Icq1; Icq1 = Icq2; Icq2 = Icq3; Icq3 = IcP;
        wcq0 = wcq1; wcq1 = wcq2; wcq2 = wcq3; wcq3 = wcP;
        snewq0 = snewq1; snewq1 = snew;
        ytq0 = ytq1; ytq1 = ytq2; ytq2 = ytq3; ytq3 = ytq4; ytq4 = ytq5; ytq5 = ytP;
        i1p = (i1p + 1 == P1c) ? 0 : i1p + 1;
        i2p = (i2p + 1 == P2c) ? 0 : i2p + 1;
        i1w = (i1w + 1 == P1c) ? 0 : i1w + 1;
        i2w = (i2w + 1 == P2c) ? 0 : i2w + 1;
    }

    // drain D for steps 510, 511
    {
        double q   = ytq0 / snewq0;
        double icn = ga * (q * pIq0) + (1.0 - ga) * Icq0;
        double wcn = om * (q * pWq0) + (1.0 - om) * wcq0;
        sIc[i1w][tid] = icn;
        sWc[i2w][tid] = wcn;
        i1w = (i1w + 1 == P1c) ? 0 : i1w + 1;
        i2w = (i2w + 1 == P2c) ? 0 : i2w + 1;
    }
    {
        double q   = ytq1 / snewq1;
        double icn = ga * (q * pIq1) + (1.0 - ga) * Icq1;
        double wcn = om * (q * pWq1) + (1.0 - om) * wcq1;
        sIc[i1w][tid] = icn;
        sWc[i2w][tid] = wcn;
    }

    // dump raw f64 state, item-major (coalesced: lanes -> consecutive series)
    #pragma unroll 8
    for (int p = 0; p < P1c; ++p)  ws[(size_t)p * NSERIES + g] = sIc[p][tid];
    #pragma unroll 8
    for (int p = 0; p < P2c; ++p)  ws[(size_t)(P1c + p) * NSERIES + g] = sWc[p][tid];
    ws[(size_t)192 * NSERIES + g] = ss;
    ws[(size_t)193 * NSERIES + g] = tt;

    out[OFF_T + bb * NFc + f] = (float)tt;
    out[OFF_S + bb * NFc + f] = (float)ss;
}

// ---------------------------------------------------------------------------
// Kernel 2: parallel epilogue — fcast + rolled Ic/wc dumps from f64 ws state.
// item in [0,530): 0..335 fcast k, 336..359 Ic j, 360..527 wc j (t,s done in k1)
// ---------------------------------------------------------------------------
__global__ __launch_bounds__(256)
void dshw_epilogue(const double* __restrict__ ws, float* __restrict__ out)
{
    const int f      = threadIdx.x & 15;
    const int isub   = threadIdx.x >> 4;        // 0..15
    const int bb     = blockIdx.x & 63;
    const int chunk  = blockIdx.x >> 6;         // 0..32
    const int item   = chunk * 16 + isub;
    const int series = bb * NFc + f;

    if (item < MAXH) {
        const int k = item;
        double cb = ws[(size_t)((k + 8) % P1c) * NSERIES + series];
        double cc = ws[(size_t)(P1c + (k + 8) % P2c) * NSERIES + series];
        double ss = ws[(size_t)192 * NSERIES + series];
        double tt = ws[(size_t)193 * NSERIES + series];
        double ca = ss + (double)(k + 1) * tt;
        out[OFF_FC + (bb * MAXH + k) * NFc + f] = (float)(ca * cb * cc);
    } else if (item < MAXH + P1c) {
        const int j = item - MAXH;
        out[OFF_IC + (bb * P1c + j) * NFc + f] =
            (float)ws[(size_t)((j + 8) % P1c) * NSERIES + series];
    } else if (item < MAXH + P1c + P2c) {
        const int j = item - (MAXH + P1c);
        out[OFF_WC + (bb * P2c + j) * NFc + f] =
            (float)ws[(size_t)(P1c + (j + 8) % P2c) * NSERIES + series];
    }
}

// ---------------------------------------------------------------------------
// Fallback (R2 fused kernel, verbatim) — used only if ws is too small.
// ---------------------------------------------------------------------------
__global__ __launch_bounds__(NT, 1)
void dshw_fused(const float* __restrict__ y,
                const float* __restrict__ alphas,
                const float* __restrict__ betas,
                const float* __restrict__ gammas,
                const float* __restrict__ omegas,
                float* __restrict__ out)
{
    __shared__ double sIc[P1c][NT];
    __shared__ double sWc[P2c][NT];

    const int tid = threadIdx.x;
    const int g   = blockIdx.x * NT + tid;
    const int bb  = g >> 4;
    const int f   = g & 15;

    const float* __restrict__ yb = y + (size_t)bb * NSTEP * NFc + f;

    const double al = 1.0 / (1.0 + exp(-(double)alphas[f]));
    const double be = 1.0 / (1.0 + exp(-(double)betas[f]));
    const double ga = 1.0 / (1.0 + exp(-(double)gammas[f]));
    const double om = 1.0 / (1.0 + exp(-(double)omegas[f]));

    double sum48 = 0.0;
    #pragma unroll
    for (int ph = 0; ph < P1c; ++ph) {
        double v0 = (double)yb[ph * NFc];
        double v1 = (double)yb[(ph + P1c) * NFc];
        sIc[ph][tid] = 0.5 * (v0 + v1);
        sum48 += v0 + v1;
    }
    const double inv_mean48 = 48.0 / sum48;
    #pragma unroll
    for (int ph = 0; ph < P1c; ++ph) sIc[ph][tid] *= inv_mean48;

    double sum168a = 0.0, sum168b = 0.0;
    for (int i = 0; i < P2c; ++i) {
        double v0 = (double)yb[i * NFc];
        double v1 = (double)yb[(i + P2c) * NFc];
        sWc[i][tid] = 0.5 * (v0 + v1);
        sum168a += v0;
        sum168b += v1;
    }
    const double mean336 = (sum168a + sum168b) * (1.0 / 336.0);
    for (int i = 0; i < P2c; ++i) {
        sWc[i][tid] = (sWc[i][tid] / mean336) / sIc[i % P1c][tid];
    }

    double tt = 0.5 * ((sum168a - sum168b) * (1.0 / (168.0 * 168.0)) +
                       ((double)yb[(P2c - 1) * NFc] - (double)yb[0]) * (1.0 / 168.0));
    double ss = mean336 - 168.5 * tt;

    float* __restrict__ yh_o = out + OFF_YH + (size_t)bb * NSTEP * NFc + f;
    float* __restrict__ e_o  = out + OFF_E  + (size_t)bb * NSTEP * NFc + f;

    int i1 = 0, i2 = 0;
    int i1p = 2, i2p = 2;

    double Icv0 = sIc[0][tid], Icv1 = sIc[1][tid];
    double wcv0 = sWc[0][tid], wcv1 = sWc[1][tid];
    double yt0 = (double)yb[0 * NFc], yt1 = (double)yb[1 * NFc];
    double yt2 = (double)yb[2 * NFc], yt3 = (double)yb[3 * NFc];

    #pragma unroll 4
    for (int step = 0; step < NSTEP; ++step) {
        double Icv2 = sIc[i1p][tid];
        double wcv2 = sWc[i2p][tid];
        int    pidx = step + 4; pidx = (pidx < NSTEP) ? pidx : (NSTEP - 1);
        double yt4  = (double)yb[pidx * NFc];

        double iw     = Icv0 * wcv0;
        double spt    = ss + tt;
        double yhat   = spt * iw;
        double inv_iw = 1.0 / iw;
        double u      = yt0 * inv_iw;
        double snew   = al * u + (1.0 - al) * spt;
        double tnew   = be * (snew - ss) + (1.0 - be) * tt;
        double q      = yt0 / snew;
        double icn    = ga * (q * (inv_iw * Icv0)) + (1.0 - ga) * Icv0;
        double wcn    = om * (q * (inv_iw * wcv0)) + (1.0 - om) * wcv0;

        sIc[i1][tid] = icn;
        sWc[i2][tid] = wcn;
        yh_o[step * NFc] = (float)yhat;
        e_o[step * NFc]  = (float)(yt0 - yhat);

        ss = snew; tt = tnew;
        Icv0 = Icv1; Icv1 = Icv2;
        wcv0 = wcv1; wcv1 = wcv2;
        yt0 = yt1; yt1 = yt2; yt2 = yt3; yt3 = yt4;
        i1  = (i1  + 1 == P1c) ? 0 : i1  + 1;
        i2  = (i2  + 1 == P2c) ? 0 : i2  + 1;
        i1p = (i1p + 1 == P1c) ? 0 : i1p + 1;
        i2p = (i2p + 1 == P2c) ? 0 : i2p + 1;
    }

    float* __restrict__ fc_o = out + OFF_FC + (size_t)bb * MAXH * NFc + f;
    {
        int k1 = 8, k2 = 8;
        for (int k = 0; k < MAXH; ++k) {
            double cb = sIc[k1][tid];
            double cc = sWc[k2][tid];
            double ca = ss + (double)(k + 1) * tt;
            fc_o[k * NFc] = (float)(ca * cb * cc);
            k1 = (k1 + 1 == P1c) ? 0 : k1 + 1;
            k2 = (k2 + 1 == P2c) ? 0 : k2 + 1;
        }
    }
    {
        float* __restrict__ ic_o = out + OFF_IC + (size_t)bb * P1c * NFc + f;
        int k1 = 8;
        #pragma unroll
        for (int j = 0; j < P1c; ++j) {
            ic_o[j * NFc] = (float)sIc[k1][tid];
            k1 = (k1 + 1 == P1c) ? 0 : k1 + 1;
        }
    }
    {
        float* __restrict__ wc_o = out + OFF_WC + (size_t)bb * P2c * NFc + f;
        int k2 = 8;
        for (int j = 0; j < P2c; ++j) {
            wc_o[j * NFc] = (float)sWc[k2][tid];
            k2 = (k2 + 1 == P2c) ? 0 : k2 + 1;
        }
    }

    out[OFF_T + bb * NFc + f] = (float)tt;
    out[OFF_S + bb * NFc + f] = (float)ss;
}

extern "C" void kernel_launch(void* const* d_in, const int* in_sizes, int n_in,
                              void* d_out, int out_size, void* d_ws, size_t ws_size,
                              hipStream_t stream)
{
    const float* y      = (const float*)d_in[0];
    const float* alphas = (const float*)d_in[1];
    const float* betas  = (const float*)d_in[2];
    const float* gammas = (const float*)d_in[3];
    const float* omegas = (const float*)d_in[4];
    float* out = (float*)d_out;

    if (ws_size >= WS_NEED) {
        dim3 grid1(NSERIES / NT);
        hipLaunchKernelGGL(dshw_scan, grid1, dim3(NT), 0, stream,
                           y, alphas, betas, gammas, omegas, out, (double*)d_ws);
        dim3 grid2(34 * BSc);   // 34 chunks of 16 items x 64 batches
        hipLaunchKernelGGL(dshw_epilogue, grid2, dim3(256), 0, stream,
                           (const double*)d_ws, out);
    } else {
        dim3 grid(NSERIES / NT);
        hipLaunchKernelGGL(dshw_fused, grid, dim3(NT), 0, stream,
                           y, alphas, betas, gammas, omegas, out);
    }
}